// Round 1
// baseline (353.131 us; speedup 1.0000x reference)
//
#include <hip/hip_runtime.h>

typedef __bf16 bf16x8 __attribute__((ext_vector_type(8)));
typedef __bf16 bf16x4 __attribute__((ext_vector_type(4)));
typedef float  floatx4 __attribute__((ext_vector_type(4)));

#define GLOBAL_AS __attribute__((address_space(1)))
#define LOCAL_AS  __attribute__((address_space(3)))

static constexpr int HID = 1024;
static constexpr int MT  = 128;   // samples per block
static constexpr int NT  = 256;   // feat cols per N-iter
static constexpr int KT  = 64;    // K per staging iter
static constexpr int NITERS = HID / NT;  // 4
static constexpr int KITERS = HID / KT;  // 16

// ---------------------------------------------------------------------------
// Prep: W2 [K][N] fp32  ->  W2T [N][K] bf16, with octet swizzle inside each
// 64-wide K tile: octet g stored at g ^ (n & 7). This makes the contiguous
// global_load_lds copy land so that B-fragment ds_read_b128 is ~conflict-free.
// ---------------------------------------------------------------------------
__global__ __launch_bounds__(256)
void prep_w2(const float* __restrict__ W2, __bf16* __restrict__ W2T) {
    __shared__ __bf16 tile[64][65];
    const int bx = blockIdx.x & 15;   // n-tile
    const int by = blockIdx.x >> 4;   // k-tile
    const int a  = threadIdx.x & 63;
    const int b  = threadIdx.x >> 6;  // 0..3
#pragma unroll
    for (int r = 0; r < 16; ++r) {
        const int k = r * 4 + b;
        tile[a][k] = (__bf16)W2[(by * 64 + k) * HID + bx * 64 + a]; // coalesced over a=n
    }
    __syncthreads();
#pragma unroll
    for (int r = 0; r < 16; ++r) {
        const int n = r * 4 + b;
        const int g = a >> 3, j = a & 7;
        const int ksw = ((g ^ (n & 7)) << 3) | j;
        W2T[(size_t)(bx * 64 + n) * HID + by * 64 + ksw] = tile[n][a];
    }
}

// ---------------------------------------------------------------------------
// Fused: h = relu(s@W1+b1) generated in-kernel -> feat = relu(h@W2+b2) via
// MFMA bf16 -> per-sample head contraction with W_heads[skill].
// ---------------------------------------------------------------------------
__device__ __forceinline__ void h8(bf16x8& d, float s0, float s1,
                                   const float4& w0a, const float4& w0b,
                                   const float4& w1a, const float4& w1b,
                                   const float4& ba,  const float4& bb) {
    d[0] = (__bf16)fmaxf(fmaf(s1, w1a.x, fmaf(s0, w0a.x, ba.x)), 0.f);
    d[1] = (__bf16)fmaxf(fmaf(s1, w1a.y, fmaf(s0, w0a.y, ba.y)), 0.f);
    d[2] = (__bf16)fmaxf(fmaf(s1, w1a.z, fmaf(s0, w0a.z, ba.z)), 0.f);
    d[3] = (__bf16)fmaxf(fmaf(s1, w1a.w, fmaf(s0, w0a.w, ba.w)), 0.f);
    d[4] = (__bf16)fmaxf(fmaf(s1, w1b.x, fmaf(s0, w0b.x, bb.x)), 0.f);
    d[5] = (__bf16)fmaxf(fmaf(s1, w1b.y, fmaf(s0, w0b.y, bb.y)), 0.f);
    d[6] = (__bf16)fmaxf(fmaf(s1, w1b.z, fmaf(s0, w0b.z, bb.z)), 0.f);
    d[7] = (__bf16)fmaxf(fmaf(s1, w1b.w, fmaf(s0, w0b.w, bb.w)), 0.f);
}

__global__ __launch_bounds__(512, 2)
void policy_fused(const float* __restrict__ S,  const int* __restrict__ SK,
                  const float* __restrict__ W1, const float* __restrict__ B1,
                  const __bf16* __restrict__ W2T, const float* __restrict__ B2,
                  const float* __restrict__ WH, const float* __restrict__ BH,
                  float* __restrict__ OUT) {
    // LDS: [hA 128x72 bf16 = 18432 | Bt 256x64 bf16 = 32768] = 51200 bytes,
    // overlaid (after barrier) by featL 128x136 bf16 = 34816 and redL 8192.
    __shared__ __align__(16) char smem[51200];
    __bf16 (*hA)[72]    = (__bf16 (*)[72])smem;
    __bf16 (*Bt)[64]    = (__bf16 (*)[64])(smem + 18432);
    __bf16 (*featL)[136] = (__bf16 (*)[136])smem;   // [col 0..127][row 0..127]
    float* redL = (float*)smem;

    const int tid  = threadIdx.x;
    const int lane = tid & 63;
    const int wave = tid >> 6;   // 0..7
    const int wm   = wave & 1;   // m strip of 64
    const int wn   = wave >> 1;  // n strip of 64 (0..3)
    const int l15  = lane & 15;
    const int quad = lane >> 4;
    const int i0   = blockIdx.x * MT;

    // h-gen assignment: thread t -> k-octet (t&7), rows (t>>3) and (t>>3)+64
    const int hg_g = tid & 7;
    const int hg_i = tid >> 3;
    const float s0a = S[(i0 + hg_i) * 2 + 0],      s1a = S[(i0 + hg_i) * 2 + 1];
    const float s0b = S[(i0 + hg_i + 64) * 2 + 0], s1b = S[(i0 + hg_i + 64) * 2 + 1];

    // head assignment: thread t -> sample (t&127), j-quarter (t>>7)
    const int hd_i = tid & 127;
    const int hd_q = tid >> 7;
    const int sk   = SK[i0 + hd_i];

    float oa0 = 0.f, oa1 = 0.f, oa2 = 0.f, oa3 = 0.f;

    for (int nt = 0; nt < NITERS; ++nt) {
        const int n0 = nt * NT;
        floatx4 acc[4][4] = {};

        for (int kt = 0; kt < KITERS; ++kt) {
            const int k0 = kt * KT;
            __syncthreads();  // previous readers (MFMA frags / featL) done

            // ---- stage A: h[128][64] bf16 into LDS (computed from s)
            {
                const int kb = k0 + hg_g * 8;
                const float4 w0a = *(const float4*)(W1 + kb);
                const float4 w0b = *(const float4*)(W1 + kb + 4);
                const float4 w1a = *(const float4*)(W1 + HID + kb);
                const float4 w1b = *(const float4*)(W1 + HID + kb + 4);
                const float4 bba = *(const float4*)(B1 + kb);
                const float4 bbb = *(const float4*)(B1 + kb + 4);
                bf16x8 ha, hb;
                h8(ha, s0a, s1a, w0a, w0b, w1a, w1b, bba, bbb);
                h8(hb, s0b, s1b, w0a, w0b, w1a, w1b, bba, bbb);
                *(bf16x8*)&hA[hg_i][hg_g * 8]      = ha;
                *(bf16x8*)&hA[hg_i + 64][hg_g * 8] = hb;
            }

            // ---- stage B: 256 rows x 128B, direct global->LDS, 4 instrs/wave
            {
                const int rbase = wave * 32;
#pragma unroll
                for (int c = 0; c < 4; ++c) {
                    const int r = rbase + c * 8 + (lane >> 3);
                    const __bf16* gp = W2T + (size_t)(n0 + r) * HID + k0 + (lane & 7) * 8;
                    __builtin_amdgcn_global_load_lds((GLOBAL_AS void*)gp,
                                                     (LOCAL_AS void*)&Bt[rbase + c * 8][0],
                                                     16, 0, 0);
                }
            }
            __syncthreads();

            // ---- MFMA: wave tile 64x64, 2 k-steps of 32
#pragma unroll
            for (int ks = 0; ks < 2; ++ks) {
                bf16x8 af[4], bfr[4];
#pragma unroll
                for (int f = 0; f < 4; ++f)
                    af[f] = *(const bf16x8*)&hA[wm * 64 + f * 16 + l15][ks * 32 + quad * 8];
#pragma unroll
                for (int f = 0; f < 4; ++f) {
                    const int nl = wn * 64 + f * 16 + l15;
                    const int gs = (ks * 4 + quad) ^ (nl & 7);  // undo storage swizzle
                    bfr[f] = *(const bf16x8*)&Bt[nl][gs * 8];
                }
#pragma unroll
                for (int fm = 0; fm < 4; ++fm)
#pragma unroll
                    for (int fn = 0; fn < 4; ++fn)
                        acc[fm][fn] = __builtin_amdgcn_mfma_f32_16x16x32_bf16(
                            af[fm], bfr[fn], acc[fm][fn], 0, 0, 0);
            }
        }

        // ---- head: relu(acc+b2) -> featL (bf16, col-major) -> dot with WH[sk]
        __syncthreads();
#pragma unroll
        for (int chunk = 0; chunk < 2; ++chunk) {
            if ((wn >> 1) == chunk) {
#pragma unroll
                for (int fn = 0; fn < 4; ++fn) {
                    const int col_l = (wn & 1) * 64 + fn * 16 + l15;   // 0..127
                    const float bb = B2[n0 + chunk * 128 + col_l];
#pragma unroll
                    for (int fm = 0; fm < 4; ++fm) {
                        const floatx4 v = acc[fm][fn];
                        bf16x4 p;
                        p[0] = (__bf16)fmaxf(v[0] + bb, 0.f);
                        p[1] = (__bf16)fmaxf(v[1] + bb, 0.f);
                        p[2] = (__bf16)fmaxf(v[2] + bb, 0.f);
                        p[3] = (__bf16)fmaxf(v[3] + bb, 0.f);
                        // C-layout rows: quad*4 + reg (within 16), col = l15
                        *(bf16x4*)&featL[col_l][wm * 64 + fm * 16 + quad * 4] = p;
                    }
                }
            }
            __syncthreads();
            {
                const float* whp = WH + (size_t)sk * (HID * 4) + (size_t)(n0 + chunk * 128) * 4;
#pragma unroll 8
                for (int jj = 0; jj < 32; ++jj) {
                    const int jl = hd_q * 32 + jj;
                    const float fv = (float)featL[jl][hd_i];
                    const float4 w = *(const float4*)(whp + jl * 4);
                    oa0 = fmaf(fv, w.x, oa0);
                    oa1 = fmaf(fv, w.y, oa1);
                    oa2 = fmaf(fv, w.z, oa2);
                    oa3 = fmaf(fv, w.w, oa3);
                }
            }
            __syncthreads();
        }
    }

    // ---- reduce the 4 j-quarters per sample, add head bias, store
    ((float4*)redL)[hd_q * 128 + hd_i] = make_float4(oa0, oa1, oa2, oa3);
    __syncthreads();
    {
        const int ri = tid >> 2, ra = tid & 3;
        const float sum = redL[(0 * 128 + ri) * 4 + ra] + redL[(1 * 128 + ri) * 4 + ra]
                        + redL[(2 * 128 + ri) * 4 + ra] + redL[(3 * 128 + ri) * 4 + ra];
        const int sk2 = SK[i0 + ri];
        OUT[(size_t)(i0 + ri) * 4 + ra] = sum + BH[sk2 * 4 + ra];
    }
}

extern "C" void kernel_launch(void* const* d_in, const int* in_sizes, int n_in,
                              void* d_out, int out_size, void* d_ws, size_t ws_size,
                              hipStream_t stream) {
    const float* S  = (const float*)d_in[0];
    const int*   SK = (const int*)d_in[1];
    const float* W1 = (const float*)d_in[2];
    const float* B1 = (const float*)d_in[3];
    const float* W2 = (const float*)d_in[4];
    const float* B2 = (const float*)d_in[5];
    const float* WH = (const float*)d_in[6];
    const float* BH = (const float*)d_in[7];
    __bf16* W2T = (__bf16*)d_ws;  // 2 MB bf16 transposed+swizzled W2

    hipLaunchKernelGGL(prep_w2, dim3(256), dim3(256), 0, stream, W2, W2T);
    hipLaunchKernelGGL(policy_fused, dim3(65536 / MT), dim3(512), 0, stream,
                       S, SK, W1, B1, W2T, B2, WH, BH, (float*)d_out);
}

// Round 2
// 349.517 us; speedup vs baseline: 1.0103x; 1.0103x over previous
//
#include <hip/hip_runtime.h>

typedef __bf16 bf16x8 __attribute__((ext_vector_type(8)));
typedef __bf16 bf16x4 __attribute__((ext_vector_type(4)));
typedef float  floatx4 __attribute__((ext_vector_type(4)));

#define GLOBAL_AS __attribute__((address_space(1)))
#define LOCAL_AS  __attribute__((address_space(3)))

static constexpr int HID = 1024;
static constexpr int MT  = 64;    // samples per block
static constexpr int NT  = 256;   // feat cols per N-iter
static constexpr int KT  = 64;    // K per staging iter
static constexpr int NITERS = HID / NT;  // 4
static constexpr int KITERS = HID / KT;  // 16

// ---------------------------------------------------------------------------
// Prep 1: W2 [K][N] fp32 -> W2T [N][K] bf16, octet g of each 64-k block stored
// at g ^ (n & 7) so global_load_lds staging + ds_read_b128 frags are
// conflict-free per 16-lane beat.
// ---------------------------------------------------------------------------
__global__ __launch_bounds__(256)
void prep_w2(const float* __restrict__ W2, __bf16* __restrict__ W2T) {
    __shared__ __bf16 tile[64][65];
    const int bx = blockIdx.x & 15;   // n-tile
    const int by = blockIdx.x >> 4;   // k-tile
    const int a  = threadIdx.x & 63;
    const int b  = threadIdx.x >> 6;  // 0..3
#pragma unroll
    for (int r = 0; r < 16; ++r) {
        const int k = r * 4 + b;
        tile[a][k] = (__bf16)W2[(by * 64 + k) * HID + bx * 64 + a]; // coalesced over a=n
    }
    __syncthreads();
#pragma unroll
    for (int r = 0; r < 16; ++r) {
        const int n = r * 4 + b;
        const int g = a >> 3, j = a & 7;
        const int ksw = ((g ^ (n & 7)) << 3) | j;
        W2T[(size_t)(bx * 64 + n) * HID + by * 64 + ksw] = tile[n][a];
    }
}

// ---------------------------------------------------------------------------
// Prep 2: W_heads [5][H][4] fp32 -> WHT [32][H] bf16 (row = skill*4+action,
// rows 20..31 zero), octet-XOR swizzle (o&7)^(r&7) within each 128-k chunk.
// ---------------------------------------------------------------------------
__global__ __launch_bounds__(256)
void prep_wh(const float* __restrict__ WH, __bf16* __restrict__ WHT) {
    const int r = blockIdx.x;          // 0..31
    const int s = r >> 2, a = r & 3;
    for (int k = threadIdx.x; k < HID; k += 256) {
        const float v = (r < 20) ? WH[((size_t)s * HID + k) * 4 + a] : 0.f;
        const int c = k >> 7, o = (k >> 3) & 15, j = k & 7;
        const int sw = (o & 8) | ((o & 7) ^ (r & 7));
        WHT[(size_t)r * HID + c * 128 + sw * 8 + j] = (__bf16)v;
    }
}

__device__ __forceinline__ void h8(bf16x8& d, float s0, float s1,
                                   const float4& w0a, const float4& w0b,
                                   const float4& w1a, const float4& w1b,
                                   const float4& ba,  const float4& bb) {
    d[0] = (__bf16)fmaxf(fmaf(s1, w1a.x, fmaf(s0, w0a.x, ba.x)), 0.f);
    d[1] = (__bf16)fmaxf(fmaf(s1, w1a.y, fmaf(s0, w0a.y, ba.y)), 0.f);
    d[2] = (__bf16)fmaxf(fmaf(s1, w1a.z, fmaf(s0, w0a.z, ba.z)), 0.f);
    d[3] = (__bf16)fmaxf(fmaf(s1, w1a.w, fmaf(s0, w0a.w, ba.w)), 0.f);
    d[4] = (__bf16)fmaxf(fmaf(s1, w1b.x, fmaf(s0, w0b.x, bb.x)), 0.f);
    d[5] = (__bf16)fmaxf(fmaf(s1, w1b.y, fmaf(s0, w0b.y, bb.y)), 0.f);
    d[6] = (__bf16)fmaxf(fmaf(s1, w1b.z, fmaf(s0, w0b.z, bb.z)), 0.f);
    d[7] = (__bf16)fmaxf(fmaf(s1, w1b.w, fmaf(s0, w0b.w, bb.w)), 0.f);
}

// ---------------------------------------------------------------------------
// Fused kernel. Operand order: mfma(W2frag, hfrag, acc) so C-layout lane holds
// sample = lane&15, featcols = quad*4+reg (contiguous) -> vectorized featL.
// Head = MFMA vs all-20-skill-cols, select per sample at the end.
// 256 threads = 4 waves; wave w owns featcol strip w*64 (main) and sample
// m-tile w*16 (head). LDS = 40960 B exactly -> 4 blocks/CU.
// ---------------------------------------------------------------------------
__global__ __launch_bounds__(256, 4)
void policy_fused(const float* __restrict__ S,  const int* __restrict__ SK,
                  const float* __restrict__ W1, const float* __restrict__ B1,
                  const __bf16* __restrict__ W2T, const float* __restrict__ B2,
                  const __bf16* __restrict__ WHT, const float* __restrict__ BH,
                  float* __restrict__ OUT) {
    __shared__ __align__(16) char smem[40960];
    __bf16* hA    = (__bf16*)smem;            // [64][64] xor-swizzled, 8192 B
    __bf16* Bt    = (__bf16*)(smem + 8192);   // [256][64] xor-swizzled, 32768 B
    __bf16* featL = (__bf16*)smem;            // overlay: [64][136] = 17408 B
    __bf16* WHTL  = (__bf16*)(smem + 17408);  // overlay: [32][128]  = 8192 B
    float*  headL = (float*)(smem + 25600);   // overlay: [32][68]f32 = 8704 B

    const int tid  = threadIdx.x;
    const int lane = tid & 63;
    const int wv   = tid >> 6;   // 0..3
    const int l15  = lane & 15;
    const int quad = lane >> 4;
    const int i0   = blockIdx.x * MT;

    // h-gen: thread t -> sample row (t>>2), octets {2*(t&3), 2*(t&3)+1}
    const int hg_i = tid >> 2;
    const int hg_g = (tid & 3) * 2;
    const float s0 = S[(i0 + hg_i) * 2 + 0];
    const float s1 = S[(i0 + hg_i) * 2 + 1];

    floatx4 hacc[2] = {};  // head acc: n-tiles 0,1 (headcols l15, 16+l15)

#pragma unroll 1
    for (int nt = 0; nt < NITERS; ++nt) {
        floatx4 acc[4][4] = {};  // [fn featcol-frag][fm sample-frag]

#pragma unroll 1
        for (int kt = 0; kt < KITERS; ++kt) {
            const int k0 = kt * KT;
            __syncthreads();  // previous readers of hA/Bt/featL/WHTL done

            // ---- stage A: h[64][64] bf16 (xor-swizzled) from s
#pragma unroll
            for (int gg = 0; gg < 2; ++gg) {
                const int g  = hg_g + gg;
                const int kb = k0 + g * 8;
                const float4 w0a = *(const float4*)(W1 + kb);
                const float4 w0b = *(const float4*)(W1 + kb + 4);
                const float4 w1a = *(const float4*)(W1 + HID + kb);
                const float4 w1b = *(const float4*)(W1 + HID + kb + 4);
                const float4 bba = *(const float4*)(B1 + kb);
                const float4 bbb = *(const float4*)(B1 + kb + 4);
                bf16x8 hv;
                h8(hv, s0, s1, w0a, w0b, w1a, w1b, bba, bbb);
                *(bf16x8*)(hA + hg_i * 64 + ((g ^ (hg_i & 7)) * 8)) = hv;
            }

            // ---- stage B: 256 rows x 128B via global_load_lds (8 instrs/thread)
#pragma unroll
            for (int c = 0; c < 8; ++c) {
                const int rb = wv * 64 + c * 8;
                const __bf16* gp = W2T + (size_t)(nt * NT + rb + (lane >> 3)) * HID
                                 + k0 + (lane & 7) * 8;
                __builtin_amdgcn_global_load_lds((GLOBAL_AS void*)gp,
                                                 (LOCAL_AS void*)(Bt + rb * 64),
                                                 16, 0, 0);
            }
            __syncthreads();

            // ---- MFMA: per wave, featcols wv*64..+63 x all 64 samples
#pragma unroll
            for (int ks = 0; ks < 2; ++ks) {
                bf16x8 wf[4], hf[4];
#pragma unroll
                for (int f = 0; f < 4; ++f) {
                    const int row = wv * 64 + f * 16 + l15;           // featcol
                    const int gs  = (ks * 4 + quad) ^ (row & 7);
                    wf[f] = *(const bf16x8*)(Bt + row * 64 + gs * 8);
                }
#pragma unroll
                for (int f = 0; f < 4; ++f) {
                    const int smp = f * 16 + l15;
                    const int o   = ks * 4 + quad;
                    hf[f] = *(const bf16x8*)(hA + smp * 64 + ((o ^ (smp & 7)) * 8));
                }
#pragma unroll
                for (int fn = 0; fn < 4; ++fn)
#pragma unroll
                    for (int fm = 0; fm < 4; ++fm)
                        acc[fn][fm] = __builtin_amdgcn_mfma_f32_16x16x32_bf16(
                            wf[fn], hf[fm], acc[fn][fm], 0, 0, 0);
            }
        }

        // ---- epilogue: featL (bf16, row-major) + head MFMA, 2 chunks of 128
#pragma unroll
        for (int chunk = 0; chunk < 2; ++chunk) {
            __syncthreads();  // prior readers (frags / head chunk0) done
            if ((wv >> 1) == chunk) {
#pragma unroll
                for (int fn = 0; fn < 4; ++fn) {
                    const int fcb = wv * 64 + fn * 16 + quad * 4 - chunk * 128; // 0..124
                    const float4 b2v = *(const float4*)(B2 + nt * NT + chunk * 128 + fcb);
#pragma unroll
                    for (int fm = 0; fm < 4; ++fm) {
                        const floatx4 v = acc[fn][fm];
                        bf16x4 p;
                        p[0] = (__bf16)fmaxf(v[0] + b2v.x, 0.f);
                        p[1] = (__bf16)fmaxf(v[1] + b2v.y, 0.f);
                        p[2] = (__bf16)fmaxf(v[2] + b2v.z, 0.f);
                        p[3] = (__bf16)fmaxf(v[3] + b2v.w, 0.f);
                        *(bf16x4*)(featL + (fm * 16 + l15) * 136 + fcb) = p;
                    }
                }
            }
            // stage WHT chunk [32][128] (2 instrs/thread)
#pragma unroll
            for (int c = 0; c < 2; ++c) {
                const int rb = wv * 8 + c * 4;
                const __bf16* gp = WHT + (size_t)(rb + (lane >> 4)) * HID
                                 + nt * NT + chunk * 128 + (lane & 15) * 8;
                __builtin_amdgcn_global_load_lds((GLOBAL_AS void*)gp,
                                                 (LOCAL_AS void*)(WHTL + rb * 128),
                                                 16, 0, 0);
            }
            __syncthreads();
            // head MFMA: wave w -> samples w*16..+15, both headcol tiles
#pragma unroll
            for (int ks2 = 0; ks2 < 4; ++ks2) {
                const bf16x8 fa = *(const bf16x8*)(featL + (wv * 16 + l15) * 136
                                                   + ks2 * 32 + quad * 8);
#pragma unroll
                for (int nt2 = 0; nt2 < 2; ++nt2) {
                    const int r = nt2 * 16 + l15;
                    const int o = ks2 * 4 + quad;
                    const int sw = (o & 8) | ((o & 7) ^ (r & 7));
                    const bf16x8 wb = *(const bf16x8*)(WHTL + r * 128 + sw * 8);
                    hacc[nt2] = __builtin_amdgcn_mfma_f32_16x16x32_bf16(
                        fa, wb, hacc[nt2], 0, 0, 0);
                }
            }
        }
    }

    // ---- select: headL[headcol][sample], then per-sample gather by skill
    __syncthreads();
#pragma unroll
    for (int nt2 = 0; nt2 < 2; ++nt2)
        *(floatx4*)(headL + (nt2 * 16 + l15) * 68 + wv * 16 + quad * 4) = hacc[nt2];
    __syncthreads();
    {
        const int smp = tid >> 2, a = tid & 3;
        const int sk  = SK[i0 + smp];
        OUT[(size_t)(i0 + smp) * 4 + a] = headL[(sk * 4 + a) * 68 + smp] + BH[sk * 4 + a];
    }
}

extern "C" void kernel_launch(void* const* d_in, const int* in_sizes, int n_in,
                              void* d_out, int out_size, void* d_ws, size_t ws_size,
                              hipStream_t stream) {
    const float* S  = (const float*)d_in[0];
    const int*   SK = (const int*)d_in[1];
    const float* W1 = (const float*)d_in[2];
    const float* B1 = (const float*)d_in[3];
    const float* W2 = (const float*)d_in[4];
    const float* B2 = (const float*)d_in[5];
    const float* WH = (const float*)d_in[6];
    const float* BH = (const float*)d_in[7];
    __bf16* W2T = (__bf16*)d_ws;                          // 2 MiB
    __bf16* WHT = (__bf16*)((char*)d_ws + 2 * 1024 * 1024); // 64 KiB

    hipLaunchKernelGGL(prep_w2, dim3(256), dim3(256), 0, stream, W2, W2T);
    hipLaunchKernelGGL(prep_wh, dim3(32), dim3(256), 0, stream, WH, WHT);
    hipLaunchKernelGGL(policy_fused, dim3(65536 / MT), dim3(256), 0, stream,
                       S, SK, W1, B1, W2T, B2, WHT, BH, (float*)d_out);
}